// Round 13
// baseline (42.781 us; speedup 1.0000x reference)
//
#include <hip/hip_runtime.h>

#pragma clang fp contract(off)

typedef unsigned long long u64;
typedef float f4 __attribute__((ext_vector_type(4)));

#define TOPK 5
#define WAVES 4   // all 4 waves share one gt, scanning disjoint pred groups

// branchless compare-exchange on u64 keys (ascending)
#define CE(x, y) do { const u64 _a = (x), _b = (y); const bool _l = _b < _a; \
                      (x) = _l ? _b : _a; (y) = _l ? _a : _b; } while (0)

// Markstein-refined division (bit-exact vs reference: absmax 0.0 in R3-R12)
__device__ __forceinline__ float fast_div(float a, float b) {
    float r = __builtin_amdgcn_rcpf(b);
    r = fmaf(fmaf(-b, r, 1.0f), r, r);
    float q = a * r;
    q = fmaf(fmaf(-b, q, a), r, q);
    return q;
}

__device__ __forceinline__ u64 eval_key(const f4 pb, const f4 gb,
                                        const float g_area, const int p) {
    const float area_p = (pb.z - pb.x) * (pb.w - pb.y);
    const float cost_bbox = fabsf(pb.x - gb.x) + fabsf(pb.y - gb.y)
                          + fabsf(pb.z - gb.z) + fabsf(pb.w - gb.w);
    const float ltx = fmaxf(pb.x, gb.x), lty = fmaxf(pb.y, gb.y);
    const float rbx = fminf(pb.z, gb.z), rby = fminf(pb.w, gb.w);
    const float iw = fmaxf(rbx - ltx, 0.0f), ih = fmaxf(rby - lty, 0.0f);
    const float inter = iw * ih;
    const float uni = area_p + g_area - inter;
    const float iou = fast_div(inter, uni);
    const float ex1 = fminf(pb.x, gb.x), ey1 = fminf(pb.y, gb.y);
    const float ex2 = fmaxf(pb.z, gb.z), ey2 = fmaxf(pb.w, gb.w);
    const float area_e = (ex2 - ex1) * (ey2 - ey1);
    const float giou = iou - fast_div(area_e - uni, area_e);
    const float cost = cost_bbox + (1.0f - giou);
    return ((u64)__float_as_uint(cost) << 32) | (unsigned)p;
}

__global__ __launch_bounds__(64 * WAVES) void matcher_topk_kernel(
    const float* __restrict__ pred_box,  // [B, NP, 4]
    const float* __restrict__ gt_box,    // [B, NG, 4]
    int* __restrict__ out_pred,          // [B, NG*TOPK]
    int* __restrict__ out_gt,            // [B, NG*TOPK]
    int B, int NP, int NG)
{
    const int task = blockIdx.x;              // one block per (b, m)
    const int t    = threadIdx.x;
    const int wid  = t >> 6;
    const int lane = t & 63;
    const int b = task / NG;
    const int m = task - b * NG;

    const f4 gb = ((const f4*)gt_box)[b * NG + m];
    const float g_area = (gb.z - gb.x) * (gb.w - gb.y);

    const int NPm1    = NP - 1;
    const int ngroups = (NP + 1023) >> 10;    // 5 for NP=5000; group = 1024 preds

    u64 k0 = ~0ULL, k1 = ~0ULL, k2 = ~0ULL, k3 = ~0ULL, k4 = ~0ULL;

    const f4* pbase = (const f4*)pred_box + (size_t)b * NP;

// inline-asm loads: compiler cannot sink/rematerialize (R6/R7/R10 lesson)
#define GLOAD(g, rA, rB, rC, rD) do {                                        \
    const int _i = ((g) << 10) + t;                                          \
    const f4* _p0 = pbase + min(_i,       NPm1);                             \
    const f4* _p1 = pbase + min(_i + 256, NPm1);                             \
    const f4* _p2 = pbase + min(_i + 512, NPm1);                             \
    const f4* _p3 = pbase + min(_i + 768, NPm1);                             \
    asm volatile("global_load_dwordx4 %0, %1, off" : "=v"(rA) : "v"(_p0));   \
    asm volatile("global_load_dwordx4 %0, %1, off" : "=v"(rB) : "v"(_p1));   \
    asm volatile("global_load_dwordx4 %0, %1, off" : "=v"(rC) : "v"(_p2));   \
    asm volatile("global_load_dwordx4 %0, %1, off" : "=v"(rD) : "v"(_p3));   \
} while (0)

// retire the oldest in-flight group (steady state 8 -> 4). sched_barrier
// right after: rule #18 (compiler hoists reg-only ops past asm waitcnt).
#define GWAIT() do {                                   \
    asm volatile("s_waitcnt vmcnt(4)");                \
    __builtin_amdgcn_sched_barrier(0);                 \
} while (0)

// 4 evals (ILP) -> mask invalid -> sort4 -> bitonic lower-5 merge into top5
#define PROCG(g, rA, rB, rC, rD) do {                                        \
    const int _i0 = ((g) << 10) + t;                                         \
    u64 kA = eval_key(rA, gb, g_area, _i0);                                  \
    u64 kB = eval_key(rB, gb, g_area, _i0 + 256);                            \
    u64 kC = eval_key(rC, gb, g_area, _i0 + 512);                            \
    u64 kD = eval_key(rD, gb, g_area, _i0 + 768);                            \
    kA = (_i0       < NP) ? kA : ~0ULL;                                      \
    kB = (_i0 + 256 < NP) ? kB : ~0ULL;                                      \
    kC = (_i0 + 512 < NP) ? kC : ~0ULL;                                      \
    kD = (_i0 + 768 < NP) ? kD : ~0ULL;                                      \
    CE(kA, kB); CE(kC, kD); CE(kA, kC); CE(kB, kD); CE(kB, kC);              \
    u64 n0 = k0;                                                             \
    u64 n1 = k1 < kD ? k1 : kD;                                              \
    u64 n2 = k2 < kC ? k2 : kC;                                              \
    u64 n3 = k3 < kB ? k3 : kB;                                              \
    u64 n4 = k4 < kA ? k4 : kA;                                              \
    CE(n0, n1); CE(n3, n4); CE(n2, n4); CE(n2, n3); CE(n1, n4);              \
    CE(n0, n3); CE(n0, n2); CE(n1, n3); CE(n1, n2);                          \
    k0 = n0; k1 = n1; k2 = n2; k3 = n3; k4 = n4;                             \
} while (0)

    f4 eA, eB, eC, eD;   // even-phase buffer
    f4 oA, oB, oC, oD;   // odd-phase buffer

    GLOAD(0, eA, eB, eC, eD);
    GLOAD(1, oA, oB, oC, oD);

    for (int g = 0; g < ngroups; g += 2) {
        GWAIT();                                // group g landed
        PROCG(g, eA, eB, eC, eD);
        __builtin_amdgcn_sched_barrier(0);      // reads of e* done before refill
        GLOAD(g + 2, eA, eB, eC, eD);           // clamped; harmless over-issue
        if (g + 1 < ngroups) {                  // uniform branch (ngroups const)
            GWAIT();                            // group g+1 landed
            PROCG(g + 1, oA, oB, oC, oD);
            __builtin_amdgcn_sched_barrier(0);
            GLOAD(g + 3, oA, oB, oC, oD);
        }
    }

    // drain in-flight loads and keep their dest regs live past the drain
    // (R11 lesson: allocator recycles them otherwise -> clobber on return)
    asm volatile("s_waitcnt vmcnt(0)");
    __builtin_amdgcn_sched_barrier(0);
    asm volatile("" :: "v"(eA), "v"(eB), "v"(eC), "v"(eD),
                       "v"(oA), "v"(oB), "v"(oC), "v"(oD));

#undef GLOAD
#undef GWAIT
#undef PROCG

    // wave butterfly: merge sorted 5-lists across all 64 lanes
    #pragma unroll
    for (int off = 1; off < 64; off <<= 1) {
        const u64 b0 = __shfl_xor(k0, off);
        const u64 b1 = __shfl_xor(k1, off);
        const u64 b2 = __shfl_xor(k2, off);
        const u64 b3 = __shfl_xor(k3, off);
        const u64 b4 = __shfl_xor(k4, off);
        u64 m0_ = k0 < b4 ? k0 : b4;
        u64 m1_ = k1 < b3 ? k1 : b3;
        u64 m2_ = k2 < b2 ? k2 : b2;
        u64 m3_ = k3 < b1 ? k3 : b1;
        u64 m4_ = k4 < b0 ? k4 : b0;
        CE(m0_, m1_); CE(m3_, m4_); CE(m2_, m4_); CE(m2_, m3_); CE(m1_, m4_);
        CE(m0_, m3_); CE(m0_, m2_); CE(m1_, m3_); CE(m1_, m2_);
        k0 = m0_; k1 = m1_; k2 = m2_; k3 = m3_; k4 = m4_;
    }

    // cross-wave merge via LDS (4 sorted 5-lists -> final 5)
    __shared__ u64 lds[WAVES][TOPK];
    if (lane == 0) {
        lds[wid][0] = k0; lds[wid][1] = k1; lds[wid][2] = k2;
        lds[wid][3] = k3; lds[wid][4] = k4;
    }
    __syncthreads();

    if (t == 0) {
        int head[WAVES];
        #pragma unroll
        for (int w = 0; w < WAVES; ++w) head[w] = 0;
        const int baseo = task * TOPK;
        #pragma unroll
        for (int r = 0; r < TOPK; ++r) {
            u64 best = ~0ULL; int bw = 0;
            #pragma unroll
            for (int w = 0; w < WAVES; ++w) {
                const u64 v = lds[w][head[w]];
                if (v < best) { best = v; bw = w; }
            }
            head[bw]++;
            out_pred[baseo + r] = (int)(unsigned)(best & 0xFFFFFFFFu);
            out_gt[baseo + r]   = m;
        }
    }
}

extern "C" void kernel_launch(void* const* d_in, const int* in_sizes, int n_in,
                              void* d_out, int out_size, void* d_ws, size_t ws_size,
                              hipStream_t stream) {
    const float* pred_box = (const float*)d_in[0];   // [B, NP, 4]
    const float* gt_box   = (const float*)d_in[2];   // [B, NG, 4]

    const int NP = 5000;
    const int B  = in_sizes[1] / NP;                 // pred_obj is [B, NP]
    const int NG = in_sizes[3] / B;                  // gt_obj is [B, NG]

    int* out_pred = (int*)d_out;
    int* out_gt   = out_pred + B * NG * TOPK;

    const int total = B * NG;                        // one block per (b, gt)
    hipLaunchKernelGGL(matcher_topk_kernel, dim3(total), dim3(64 * WAVES), 0, stream,
                       pred_box, gt_box, out_pred, out_gt, B, NP, NG);
}